// Round 2
// baseline (434.946 us; speedup 1.0000x reference)
//
#include <hip/hip_runtime.h>
#include <hip/hip_bf16.h>
#include <math.h>

typedef unsigned short u16;
typedef unsigned int u32;
typedef unsigned long long u64;
typedef signed char i8;

constexpr int NB = 64, NS = 128, NDM = 1024, NH = 16, NDK = 64;
constexpr int NM = NB * NS;  // 8192
constexpr float QEPS = 1e-8f;

typedef __attribute__((ext_vector_type(8))) short short8;
typedef __attribute__((ext_vector_type(4))) float f32x4;
typedef __attribute__((ext_vector_type(4))) int i32x4;

__device__ __forceinline__ u32 fenc(float f) {
  u32 u = __float_as_uint(f);
  return (u & 0x80000000u) ? ~u : (u | 0x80000000u);
}
__device__ __forceinline__ float fdec(u32 u) {
  u = (u & 0x80000000u) ? (u & 0x7FFFFFFFu) : ~u;
  return __uint_as_float(u);
}
// quantized values are small integers -> exact bf16 truncation
__device__ __forceinline__ u16 f2bf(float f) { return (u16)(__float_as_uint(f) >> 16); }
__device__ __forceinline__ float bf2f(u16 u) { return __uint_as_float(((u32)u) << 16); }

// async global->LDS, 16B per lane; lds dest = wave-uniform base + lane*16
__device__ __forceinline__ void glds16(const void* g, void* l) {
  __builtin_amdgcn_global_load_lds(
      (const __attribute__((address_space(1))) void*)(unsigned long long)(uintptr_t)g,
      (__attribute__((address_space(3))) void*)(u32)(uintptr_t)l, 16, 0, 0);
}

// ---- scale slots (u32/float at ws offset 0) ----
// [0..2] enc max(q,k,v)  [3..6] enc absmax(W*)  [7] enc max(x)
// [8..135] absmax_q per s; [136..263] absmax_k; [264..391] absmax_v (plain float bits)
// [392..519] colmax_p per j (plain float bits)

// mask[B,S,S] int32 -> bitmask [B*S][2] u64; block 0 also zeroes the scale slots
__global__ void maskbits_kernel(const int* __restrict__ mask, u64* __restrict__ mb,
                                u32* __restrict__ scl) {
  if (blockIdx.x == 0) {
    for (int i = threadIdx.x; i < 2048; i += blockDim.x) scl[i] = 0u;
  }
  int row = blockIdx.x * 4 + (threadIdx.x >> 6);
  int lane = threadIdx.x & 63;
  const int* mrow = mask + (size_t)row * NS;
  u64 b0 = __ballot(mrow[lane] != 0);
  u64 b1 = __ballot(mrow[64 + lane] != 0);
  if (lane == 0) { mb[row * 2] = b0; mb[row * 2 + 1] = b1; }
}

// fused 7-way max reduce: y=0..2 max(q,k,v); y=3..6 absmax(Wq..Wo)
__global__ void fused_max_kernel(const float* __restrict__ q, const float* __restrict__ k,
                                 const float* __restrict__ v, const float* __restrict__ w0,
                                 const float* __restrict__ w1, const float* __restrict__ w2,
                                 const float* __restrict__ w3, u32* __restrict__ sclu) {
  int y = blockIdx.y;
  const float* src; size_t n4; int ab;
  switch (y) {
    case 0: src = q; n4 = (size_t)NM * NDM / 4; ab = 0; break;
    case 1: src = k; n4 = (size_t)NM * NDM / 4; ab = 0; break;
    case 2: src = v; n4 = (size_t)NM * NDM / 4; ab = 0; break;
    case 3: src = w0; n4 = (size_t)NDM * NDM / 4; ab = 1; break;
    case 4: src = w1; n4 = (size_t)NDM * NDM / 4; ab = 1; break;
    case 5: src = w2; n4 = (size_t)NDM * NDM / 4; ab = 1; break;
    default: src = w3; n4 = (size_t)NDM * NDM / 4; ab = 1; break;
  }
  float m = -INFINITY;
  size_t stride = (size_t)gridDim.x * blockDim.x;
  for (size_t i = (size_t)blockIdx.x * blockDim.x + threadIdx.x; i < n4; i += stride) {
    float4 f = ((const float4*)src)[i];
    if (ab) { f.x = fabsf(f.x); f.y = fabsf(f.y); f.z = fabsf(f.z); f.w = fabsf(f.w); }
    m = fmaxf(m, fmaxf(fmaxf(f.x, f.y), fmaxf(f.z, f.w)));
  }
  for (int off = 32; off; off >>= 1) m = fmaxf(m, __shfl_down(m, off));
  __shared__ float sm[4];
  if ((threadIdx.x & 63) == 0) sm[threadIdx.x >> 6] = m;
  __syncthreads();
  if (threadIdx.x == 0) {
    float r = fmaxf(fmaxf(sm[0], sm[1]), fmaxf(sm[2], sm[3]));
    atomicMax(&sclu[y], fenc(r));
  }
}

// weight quant -> i8 (-127..127) + per-output-channel column sums (for u8 shift fix)
__global__ __launch_bounds__(256)
void quant_w_i8_kernel(const float* __restrict__ w0, const float* __restrict__ w1,
                       const float* __restrict__ w2, const float* __restrict__ w3,
                       i8* __restrict__ dst, int* __restrict__ colsum,
                       const u32* __restrict__ sclu) {
  int y = blockIdx.y, row = blockIdx.x, tid = threadIdx.x;
  const float* src = (y == 0 ? w0 : y == 1 ? w1 : y == 2 ? w2 : w3) + (size_t)row * NDM;
  float s = fmaxf(fdec(sclu[3 + y]), QEPS) / 127.0f;
  float4 f = ((const float4*)src)[tid];
  int a = (int)fminf(fmaxf(rintf(f.x / s), -127.f), 127.f);
  int b = (int)fminf(fmaxf(rintf(f.y / s), -127.f), 127.f);
  int c = (int)fminf(fmaxf(rintf(f.z / s), -127.f), 127.f);
  int d = (int)fminf(fmaxf(rintf(f.w / s), -127.f), 127.f);
  ((int*)(dst + (size_t)y * NDM * NDM + (size_t)row * NDM))[tid] =
      (a & 255) | ((b & 255) << 8) | ((c & 255) << 16) | ((d & 255) << 24);
  int ssum = a + b + c + d;
  for (int off = 32; off; off >>= 1) ssum += __shfl_down(ssum, off);
  __shared__ int sm[4];
  if ((tid & 63) == 0) sm[tid >> 6] = ssum;
  __syncthreads();
  if (tid == 0) colsum[y * NDM + row] = sm[0] + sm[1] + sm[2] + sm[3];
}

// uint8 activation fake-quant -> shifted i8 (q-128); y selects source/slot/dst
__global__ void quant_a_kernel(const float* __restrict__ s0, const float* __restrict__ s1,
                               const float* __restrict__ s2, i8* __restrict__ dst,
                               const u32* __restrict__ sclu, int slot_base) {
  int y = blockIdx.y;
  const float* src = y == 0 ? s0 : y == 1 ? s1 : s2;
  i8* d = dst + (size_t)y * NM * NDM;
  float s = fmaxf(fdec(sclu[slot_base + y]), QEPS) / 255.0f;
  size_t n4 = (size_t)NM * NDM / 4;
  size_t stride = (size_t)gridDim.x * blockDim.x;
  for (size_t i = (size_t)blockIdx.x * blockDim.x + threadIdx.x; i < n4; i += stride) {
    float4 f = ((const float4*)src)[i];
    int a = (int)fminf(fmaxf(rintf(f.x / s), 0.f), 255.f) - 128;
    int b = (int)fminf(fmaxf(rintf(f.y / s), 0.f), 255.f) - 128;
    int c = (int)fminf(fmaxf(rintf(f.z / s), 0.f), 255.f) - 128;
    int e = (int)fminf(fmaxf(rintf(f.w / s), 0.f), 255.f) - 128;
    ((int*)d)[i] = (a & 255) | ((b & 255) << 8) | ((c & 255) << 16) | ((e & 255) << 24);
  }
}

// proj fp32 -> int8 with per-s scale; y=0..2 selects q/k/v
__global__ void qkv_i8_kernel(const float* __restrict__ projbase, i8* __restrict__ dstbase,
                              const float* __restrict__ scl) {
  int y = blockIdx.y;
  const float* src = projbase + (size_t)y * NM * NDM;
  i8* dst = dstbase + (size_t)y * NM * NDM;
  const float* sb = scl + 8 + y * 128;
  size_t n4 = (size_t)NM * NDM / 4;
  size_t stride = (size_t)gridDim.x * blockDim.x;
  for (size_t i = (size_t)blockIdx.x * blockDim.x + threadIdx.x; i < n4; i += stride) {
    int s_idx = (int)((i >> 8) & 127);
    float s = fmaxf(sb[s_idx], QEPS) / 127.0f;
    float4 f = ((const float4*)src)[i];
    int a = (int)fminf(fmaxf(rintf(f.x / s), -128.f), 127.f);
    int b = (int)fminf(fmaxf(rintf(f.y / s), -128.f), 127.f);
    int c = (int)fminf(fmaxf(rintf(f.z / s), -128.f), 127.f);
    int d = (int)fminf(fmaxf(rintf(f.w / s), -128.f), 127.f);
    ((int*)dst)[i] = (a & 255) | ((b & 255) << 8) | ((c & 255) << 16) | ((d & 255) << 24);
  }
}

// ---------------- GEMM: i8 MFMA, K=64/iter, m97 staging ----------------
constexpr int BM = 128, BN = 128, BK = 64;

template <bool PROJ>
__global__ __launch_bounds__(256)
void gemm_kernel(const i8* __restrict__ Abase, const i8* __restrict__ Wbase,
                 const int* __restrict__ colsum, const float* __restrict__ b0,
                 const float* __restrict__ b1, const float* __restrict__ b2,
                 float* __restrict__ Cbase, u32* __restrict__ sclu) {
  constexpr int K = NDM, N = NDM;
  const int z = PROJ ? blockIdx.z : 0;
  const i8* A = Abase + (size_t)z * NM * NDM;
  const i8* Wt = PROJ ? (Wbase + (size_t)z * NDM * NDM) : Wbase;
  const float* bias = PROJ ? (z == 0 ? b0 : z == 1 ? b1 : b2) : b0;
  float* C = PROJ ? (Cbase + (size_t)z * NM * NDM) : Cbase;
  const u32* slot_in = PROJ ? (sclu + z) : (sclu + 7);
  const u32* slot_w = PROJ ? (sclu + 3 + z) : (sclu + 6);
  const int* cs = colsum + (PROJ ? z : 3) * NDM;

  __shared__ __align__(16) i8 As[BM][BK];  // 8 KB, contiguous (global_load_lds dest)
  __shared__ __align__(16) i8 Bs[BN][BK];
  __shared__ float rmax2[2][BM];

  const int tid = threadIdx.x;
  const int lane = tid & 63, wave = tid >> 6;
  const int wm = (wave & 1) * 64, wn = (wave >> 1) * 64;
  const int r16 = lane & 15, quad = lane >> 4;
  const int bm = blockIdx.x * BM, bn = blockIdx.y * BN;

  i32x4 acc[4][4] = {};

  const int lrow = lane >> 2, lcol = (lane & 3) * 16;  // 16 rows per glds16, 64B rows
  for (int k0 = 0; k0 < K; k0 += BK) {
    __syncthreads();
#pragma unroll
    for (int p = 0; p < 2; p++) {
      int r = wave * 32 + p * 16;
      glds16(A + (size_t)(bm + r + lrow) * K + k0 + lcol, &As[r][0]);
      glds16(Wt + (size_t)(bn + r + lrow) * K + k0 + lcol, &Bs[r][0]);
    }
    __syncthreads();
    i32x4 af[4], bfr[4];
#pragma unroll
    for (int i = 0; i < 4; i++) af[i] = *(const i32x4*)(&As[wm + i * 16 + r16][quad * 16]);
#pragma unroll
    for (int j = 0; j < 4; j++) bfr[j] = *(const i32x4*)(&Bs[wn + j * 16 + r16][quad * 16]);
#pragma unroll
    for (int i = 0; i < 4; i++)
#pragma unroll
      for (int j = 0; j < 4; j++)
        acc[i][j] = __builtin_amdgcn_mfma_i32_16x16x64_i8(af[i], bfr[j], acc[i][j], 0, 0, 0);
  }

  float s_in = fmaxf(fdec(*slot_in), QEPS) / 255.0f;
  float s_w = fmaxf(fdec(*slot_w), QEPS) / 127.0f;
  float sc = s_in * s_w;

  float bq[4];
  int csj[4];
#pragma unroll
  for (int j = 0; j < 4; j++) {
    int gc = bn + wn + j * 16 + r16;
    bq[j] = rintf(bias[gc] / sc) * sc;
    csj[j] = cs[gc] << 7;  // +128 * colsum(W): undoes the x-128 input shift
  }
#pragma unroll
  for (int i = 0; i < 4; i++) {
#pragma unroll
    for (int r = 0; r < 4; r++) {
      int lr = wm + i * 16 + quad * 4 + r;
      int gr = bm + lr;
      float rm = 0.0f;
#pragma unroll
      for (int j = 0; j < 4; j++) {
        int gc = bn + wn + j * 16 + r16;
        float val = (float)(acc[i][j][r] + csj[j]) * sc + bq[j];
        C[(size_t)gr * N + gc] = val;
        if (PROJ) rm = fmaxf(rm, fabsf(val));
      }
      if (PROJ) {
#pragma unroll
        for (int off = 1; off < 16; off <<= 1) rm = fmaxf(rm, __shfl_xor(rm, off));
        if (r16 == 0) rmax2[wave >> 1][lr] = rm;
      }
    }
  }
  if (PROJ) {
    __syncthreads();
    if (tid < BM) {
      float m = fmaxf(rmax2[0][tid], rmax2[1][tid]);
      atomicMax((int*)&sclu[8 + z * 128 + tid], __float_as_int(m));  // m >= 0
    }
  }
}

// ---------------- attention ----------------
// Phase 1: QK^T + softmax, colmax atomics only (P is NOT materialized)
__global__ __launch_bounds__(256)
void attn_colmax_kernel(const i8* __restrict__ qi8, const i8* __restrict__ ki8,
                        const u64* __restrict__ mb, const float* __restrict__ scl,
                        u32* __restrict__ sclu) {
  const int bh = blockIdx.x, b = bh >> 4, h = bh & 15;
  const int tid = threadIdx.x, lane = tid & 63, wave = tid >> 6;
  const int r16 = lane & 15, quad = lane >> 4;

  __shared__ __align__(16) i8 Qs[NS][80];
  __shared__ __align__(16) i8 Ks[NS][80];
  __shared__ float sqv[NS], skv[NS];
  __shared__ float cmw[4][NS];

  {
    int row = tid >> 1, half = (tid & 1) * 32;
    const i8* qp = qi8 + (size_t)(b * NS + row) * NDM + h * NDK + half;
    const i8* kp = ki8 + (size_t)(b * NS + row) * NDM + h * NDK + half;
    *(int4*)&Qs[row][half] = *(const int4*)qp;
    *(int4*)&Qs[row][half + 16] = *(const int4*)(qp + 16);
    *(int4*)&Ks[row][half] = *(const int4*)kp;
    *(int4*)&Ks[row][half + 16] = *(const int4*)(kp + 16);
    if (tid < NS) {
      sqv[tid] = fmaxf(scl[8 + tid], QEPS) / 127.0f;
      skv[tid] = fmaxf(scl[8 + 128 + tid], QEPS) / 127.0f;
    }
  }
  __syncthreads();

  const int rowbase = wave * 32;
  i32x4 acc[2][8] = {};
#pragma unroll
  for (int mt = 0; mt < 2; mt++) {
    i32x4 a = *(const i32x4*)&Qs[rowbase + mt * 16 + r16][quad * 16];
#pragma unroll
    for (int nt = 0; nt < 8; nt++) {
      i32x4 bfrag = *(const i32x4*)&Ks[nt * 16 + r16][quad * 16];
      acc[mt][nt] = __builtin_amdgcn_mfma_i32_16x16x64_i8(a, bfrag, acc[mt][nt], 0, 0, 0);
    }
  }

  float skc[8], cm[8];
#pragma unroll
  for (int nt = 0; nt < 8; nt++) { skc[nt] = skv[nt * 16 + r16]; cm[nt] = 0.0f; }

#pragma unroll
  for (int mt = 0; mt < 2; mt++) {
#pragma unroll
    for (int r = 0; r < 4; r++) {
      int row = rowbase + mt * 16 + quad * 4 + r;
      float sq = sqv[row];
      const u64* mrow = mb + ((size_t)b * NS + row) * 2;
      u64 m0 = mrow[0], m1 = mrow[1];
      float vals[8];
      float mx = -INFINITY;
#pragma unroll
      for (int nt = 0; nt < 8; nt++) {
        float v = (float)acc[mt][nt][r] * (sq * skc[nt]) * 0.125f;
        u64 bits = nt < 4 ? m0 : m1;
        if (((bits >> ((nt * 16 + r16) & 63)) & 1ull) == 0) v = -1e9f;
        vals[nt] = v;
        mx = fmaxf(mx, v);
      }
#pragma unroll
      for (int off = 1; off < 16; off <<= 1) mx = fmaxf(mx, __shfl_xor(mx, off));
      float sum = 0.0f;
#pragma unroll
      for (int nt = 0; nt < 8; nt++) { vals[nt] = __expf(vals[nt] - mx); sum += vals[nt]; }
#pragma unroll
      for (int off = 1; off < 16; off <<= 1) sum += __shfl_xor(sum, off);
#pragma unroll
      for (int nt = 0; nt < 8; nt++) {
        float p = vals[nt] / sum;
        cm[nt] = fmaxf(cm[nt], p);
      }
    }
  }

#pragma unroll
  for (int nt = 0; nt < 8; nt++) {
    float c = cm[nt];
    c = fmaxf(c, __shfl_xor(c, 16));
    c = fmaxf(c, __shfl_xor(c, 32));
    if (quad == 0) cmw[wave][nt * 16 + r16] = c;
  }
  __syncthreads();
  if (tid < NS) {
    float c = fmaxf(fmaxf(cmw[0][tid], cmw[1][tid]), fmaxf(cmw[2][tid], cmw[3][tid]));
    atomicMax((int*)&sclu[392 + tid], __float_as_int(c));  // p >= 0
  }
}

// Phase 2: recompute QK^T + softmax (bitwise-identical to phase 1), quantize P with
// final colmax scales directly into LDS, then PV. No Pn HBM round-trip.
__global__ __launch_bounds__(256)
void attn_pv2_kernel(const i8* __restrict__ qi8, const i8* __restrict__ ki8,
                     const i8* __restrict__ vi8, const u64* __restrict__ mb,
                     const float* __restrict__ scl, float* __restrict__ xout,
                     u32* __restrict__ xmax_slot) {
  const int bh = blockIdx.x, b = bh >> 4, h = bh & 15;
  const int tid = threadIdx.x, lane = tid & 63, wave = tid >> 6;
  const int r16 = lane & 15, quad = lane >> 4;
  const int rowbase = wave * 32;

  union SU {
    struct { i8 Q[NS][80]; i8 K[NS][80]; } qk;      // 20.5 KB (QK^T phase)
    struct { u16 hi[64][72]; u16 lo[64][72]; } v;   // 18.4 KB (PV phase)
  };
  __shared__ __align__(16) SU u;
  __shared__ __align__(16) u16 Ps[NS][136];  // 34 KB; stride 136 u16 = 272 B (16B-aligned)
  __shared__ float sqv[NS], skv[NS], spv[NS], svv[NS];

  {
    int row = tid >> 1, half = (tid & 1) * 32;
    const i8* qp = qi8 + (size_t)(b * NS + row) * NDM + h * NDK + half;
    const i8* kp = ki8 + (size_t)(b * NS + row) * NDM + h * NDK + half;
    *(int4*)&u.qk.Q[row][half] = *(const int4*)qp;
    *(int4*)&u.qk.Q[row][half + 16] = *(const int4*)(qp + 16);
    *(int4*)&u.qk.K[row][half] = *(const int4*)kp;
    *(int4*)&u.qk.K[row][half + 16] = *(const int4*)(kp + 16);
    if (tid < NS) {
      sqv[tid] = fmaxf(scl[8 + tid], QEPS) / 127.0f;
      skv[tid] = fmaxf(scl[8 + 128 + tid], QEPS) / 127.0f;
      spv[tid] = fmaxf(scl[392 + tid], QEPS) / 127.0f;
      svv[tid] = fmaxf(scl[8 + 256 + tid], QEPS) / 127.0f;
    }
  }
  __syncthreads();

  i32x4 acc[2][8] = {};
#pragma unroll
  for (int mt = 0; mt < 2; mt++) {
    i32x4 a = *(const i32x4*)&u.qk.Q[rowbase + mt * 16 + r16][quad * 16];
#pragma unroll
    for (int nt = 0; nt < 8; nt++) {
      i32x4 bfrag = *(const i32x4*)&u.qk.K[nt * 16 + r16][quad * 16];
      acc[mt][nt] = __builtin_amdgcn_mfma_i32_16x16x64_i8(a, bfrag, acc[mt][nt], 0, 0, 0);
    }
  }

  float skc[8], spc[8];
#pragma unroll
  for (int nt = 0; nt < 8; nt++) {
    skc[nt] = skv[nt * 16 + r16];
    spc[nt] = spv[nt * 16 + r16];
  }

#pragma unroll
  for (int mt = 0; mt < 2; mt++) {
#pragma unroll
    for (int r = 0; r < 4; r++) {
      int row = rowbase + mt * 16 + quad * 4 + r;
      float sq = sqv[row];
      const u64* mrow = mb + ((size_t)b * NS + row) * 2;
      u64 m0 = mrow[0], m1 = mrow[1];
      float vals[8];
      float mx = -INFINITY;
#pragma unroll
      for (int nt = 0; nt < 8; nt++) {
        float v = (float)acc[mt][nt][r] * (sq * skc[nt]) * 0.125f;
        u64 bits = nt < 4 ? m0 : m1;
        if (((bits >> ((nt * 16 + r16) & 63)) & 1ull) == 0) v = -1e9f;
        vals[nt] = v;
        mx = fmaxf(mx, v);
      }
#pragma unroll
      for (int off = 1; off < 16; off <<= 1) mx = fmaxf(mx, __shfl_xor(mx, off));
      float sum = 0.0f;
#pragma unroll
      for (int nt = 0; nt < 8; nt++) { vals[nt] = __expf(vals[nt] - mx); sum += vals[nt]; }
#pragma unroll
      for (int off = 1; off < 16; off <<= 1) sum += __shfl_xor(sum, off);
#pragma unroll
      for (int nt = 0; nt < 8; nt++) {
        float p = vals[nt] / sum;  // bitwise equal to phase-1 p
        float pq = fminf(fmaxf(rintf(p / spc[nt]), -128.f), 127.f);
        Ps[row][nt * 16 + r16] = f2bf(pq);  // small ints: exact in bf16
      }
    }
  }
  // Ps complete per-wave for its own rows; sync below also fences Q/K reads
  // before the union is overwritten with V.

  f32x4 xacc[2][4] = {};
#pragma unroll
  for (int half = 0; half < 2; half++) {
    __syncthreads();
    {
      int jl = tid >> 2, d0 = (tid & 3) * 16;
      int j = half * 64 + jl;
      float g = spv[j] * svv[j];
      const i8* vp = vi8 + (size_t)(b * NS + j) * NDM + h * NDK + d0;
      int4 raw = *(const int4*)vp;
      const i8* rb = (const i8*)&raw;
#pragma unroll
      for (int d = 0; d < 16; d++) {
        float w = (float)rb[d] * g;
        u16 hi = f2bf(w);
        u.v.hi[d0 + d][jl] = hi;
        u.v.lo[d0 + d][jl] = f2bf(w - bf2f(hi));
      }
    }
    __syncthreads();
#pragma unroll
    for (int kk = 0; kk < 2; kk++) {
      short8 pa[2];
#pragma unroll
      for (int mt = 0; mt < 2; mt++)
        pa[mt] = *(const short8*)&Ps[rowbase + mt * 16 + r16][half * 64 + kk * 32 + quad * 8];
#pragma unroll
      for (int nt = 0; nt < 4; nt++) {
        short8 vh = *(const short8*)&u.v.hi[nt * 16 + r16][kk * 32 + quad * 8];
        short8 vl = *(const short8*)&u.v.lo[nt * 16 + r16][kk * 32 + quad * 8];
#pragma unroll
        for (int mt = 0; mt < 2; mt++) {
          xacc[mt][nt] = __builtin_amdgcn_mfma_f32_16x16x32_bf16(pa[mt], vh, xacc[mt][nt], 0, 0, 0);
          xacc[mt][nt] = __builtin_amdgcn_mfma_f32_16x16x32_bf16(pa[mt], vl, xacc[mt][nt], 0, 0, 0);
        }
      }
    }
  }

  float mx = -INFINITY;
#pragma unroll
  for (int mt = 0; mt < 2; mt++)
#pragma unroll
    for (int nt = 0; nt < 4; nt++)
#pragma unroll
      for (int r = 0; r < 4; r++) {
        int row = rowbase + mt * 16 + quad * 4 + r;
        xout[((size_t)b * NS + row) * NDM + h * NDK + nt * 16 + r16] = xacc[mt][nt][r];
        mx = fmaxf(mx, xacc[mt][nt][r]);
      }
#pragma unroll
  for (int off = 1; off < 64; off <<= 1) mx = fmaxf(mx, __shfl_xor(mx, off));
  if (lane == 0) atomicMax(xmax_slot, fenc(mx));
}

// ---------------- workspace layout ----------------
constexpr size_t OFF_SCL = 0;                                   // 8 KB (2048 u32)
constexpr size_t OFF_CS  = 8192;                                // colsum 4x1024 int = 16 KB
constexpr size_t OFF_MB  = OFF_CS + 4 * NDM * 4;                // mask bits 128 KB
constexpr size_t OFF_W   = OFF_MB + (size_t)NM * 16;            // i8 weights 4 MB
constexpr size_t OFF_XQ  = OFF_W + 4 * (size_t)NDM * NDM;       // i8 acts 3x8 MB
constexpr size_t OFF_PQ  = OFF_XQ + 3 * (size_t)NM * NDM;       // f32 proj 3x33.5 MB
constexpr size_t OFF_I8  = OFF_PQ + 3 * (size_t)NM * NDM * 4;   // attn i8 qkv 3x8 MB
// xout aliases projv (dead after qkv_i8); P is never materialized (flash recompute)

extern "C" void kernel_launch(void* const* d_in, const int* in_sizes, int n_in,
                              void* d_out, int out_size, void* d_ws, size_t ws_size,
                              hipStream_t stream) {
  const float* query = (const float*)d_in[0];
  const float* key = (const float*)d_in[1];
  const float* value = (const float*)d_in[2];
  const int* mask = (const int*)d_in[3];
  const float* Wq = (const float*)d_in[4]; const float* bq = (const float*)d_in[5];
  const float* Wk = (const float*)d_in[6]; const float* bk = (const float*)d_in[7];
  const float* Wv = (const float*)d_in[8]; const float* bv = (const float*)d_in[9];
  const float* Wo = (const float*)d_in[10]; const float* bo = (const float*)d_in[11];

  char* ws = (char*)d_ws;
  float* scl = (float*)(ws + OFF_SCL);
  u32* sclu = (u32*)scl;
  int* colsum = (int*)(ws + OFF_CS);
  u64* mb = (u64*)(ws + OFF_MB);
  i8* wb = (i8*)(ws + OFF_W);        // wq|wk|wv|wo
  i8* wob = wb + 3 * (size_t)NDM * NDM;
  i8* xq = (i8*)(ws + OFF_XQ);       // q|k|v shifted i8 (slot 0 reused for x)
  float* proj = (float*)(ws + OFF_PQ);
  i8* qkv8 = (i8*)(ws + OFF_I8);
  float* xout = proj + 2 * (size_t)NM * NDM;
  i8* vi8 = qkv8 + 2 * (size_t)NM * NDM;

  maskbits_kernel<<<NM / 4, 256, 0, stream>>>(mask, mb, sclu);
  fused_max_kernel<<<dim3(512, 7), 256, 0, stream>>>(query, key, value, Wq, Wk, Wv, Wo, sclu);
  quant_w_i8_kernel<<<dim3(NDM, 4), 256, 0, stream>>>(Wq, Wk, Wv, Wo, wb, colsum, sclu);
  quant_a_kernel<<<dim3(512, 3), 256, 0, stream>>>(query, key, value, xq, sclu, 0);

  gemm_kernel<true><<<dim3(NM / BM, NDM / BN, 3), 256, 0, stream>>>(
      xq, wb, colsum, bq, bk, bv, proj, sclu);

  qkv_i8_kernel<<<dim3(512, 3), 256, 0, stream>>>(proj, qkv8, scl);

  attn_colmax_kernel<<<NB * NH, 256, 0, stream>>>(qkv8, qkv8 + (size_t)NM * NDM, mb, scl,
                                                  sclu);
  attn_pv2_kernel<<<NB * NH, 256, 0, stream>>>(qkv8, qkv8 + (size_t)NM * NDM, vi8, mb, scl,
                                               xout, sclu + 7);

  quant_a_kernel<<<dim3(512, 1), 256, 0, stream>>>(xout, xout, xout, xq, sclu, 7);
  gemm_kernel<false><<<dim3(NM / BM, NDM / BN, 1), 256, 0, stream>>>(
      xq, wob, colsum, bo, bo, bo, (float*)d_out, sclu);
}

// Round 5
// 423.375 us; speedup vs baseline: 1.0273x; 1.0273x over previous
//
#include <hip/hip_runtime.h>
#include <hip/hip_bf16.h>
#include <math.h>

typedef unsigned short u16;
typedef unsigned int u32;
typedef unsigned long long u64;
typedef signed char i8;

constexpr int NB = 64, NS = 128, NDM = 1024, NH = 16, NDK = 64;
constexpr int NM = NB * NS;  // 8192
constexpr float QEPS = 1e-8f;

typedef __attribute__((ext_vector_type(8))) short short8;
typedef __attribute__((ext_vector_type(4))) float f32x4;
typedef __attribute__((ext_vector_type(4))) int i32x4;

__device__ __forceinline__ u32 fenc(float f) {
  u32 u = __float_as_uint(f);
  return (u & 0x80000000u) ? ~u : (u | 0x80000000u);
}
__device__ __forceinline__ float fdec(u32 u) {
  u = (u & 0x80000000u) ? (u & 0x7FFFFFFFu) : ~u;
  return __uint_as_float(u);
}
// quantized values are small integers -> exact bf16 truncation
__device__ __forceinline__ u16 f2bf(float f) { return (u16)(__float_as_uint(f) >> 16); }
__device__ __forceinline__ float bf2f(u16 u) { return __uint_as_float(((u32)u) << 16); }

// async global->LDS, 16B per lane; lds dest = wave-uniform base + lane*16
__device__ __forceinline__ void glds16(const void* g, void* l) {
  __builtin_amdgcn_global_load_lds(
      (const __attribute__((address_space(1))) void*)(unsigned long long)(uintptr_t)g,
      (__attribute__((address_space(3))) void*)(u32)(uintptr_t)l, 16, 0, 0);
}

// ---- scale slots (u32/float at ws offset 0) ----
// [0..2] enc max(q,k,v)  [3..6] enc absmax(W*)  [7] enc max(x)
// [8..135] absmax_q per s; [136..263] absmax_k; [264..391] absmax_v (plain float bits)
// [392..519] colmax_p per j (plain float bits)

// mask[B,S,S] int32 -> bitmask [B*S][2] u64; block 0 also zeroes the scale slots
__global__ void maskbits_kernel(const int* __restrict__ mask, u64* __restrict__ mb,
                                u32* __restrict__ scl) {
  if (blockIdx.x == 0) {
    for (int i = threadIdx.x; i < 2048; i += blockDim.x) scl[i] = 0u;
  }
  int row = blockIdx.x * 4 + (threadIdx.x >> 6);
  int lane = threadIdx.x & 63;
  const int* mrow = mask + (size_t)row * NS;
  u64 b0 = __ballot(mrow[lane] != 0);
  u64 b1 = __ballot(mrow[64 + lane] != 0);
  if (lane == 0) { mb[row * 2] = b0; mb[row * 2 + 1] = b1; }
}

// fused 7-way max reduce: y=0..2 max(q,k,v); y=3..6 absmax(Wq..Wo)
__global__ void fused_max_kernel(const float* __restrict__ q, const float* __restrict__ k,
                                 const float* __restrict__ v, const float* __restrict__ w0,
                                 const float* __restrict__ w1, const float* __restrict__ w2,
                                 const float* __restrict__ w3, u32* __restrict__ sclu) {
  int y = blockIdx.y;
  const float* src; size_t n4; int ab;
  switch (y) {
    case 0: src = q; n4 = (size_t)NM * NDM / 4; ab = 0; break;
    case 1: src = k; n4 = (size_t)NM * NDM / 4; ab = 0; break;
    case 2: src = v; n4 = (size_t)NM * NDM / 4; ab = 0; break;
    case 3: src = w0; n4 = (size_t)NDM * NDM / 4; ab = 1; break;
    case 4: src = w1; n4 = (size_t)NDM * NDM / 4; ab = 1; break;
    case 5: src = w2; n4 = (size_t)NDM * NDM / 4; ab = 1; break;
    default: src = w3; n4 = (size_t)NDM * NDM / 4; ab = 1; break;
  }
  float m = -INFINITY;
  size_t stride = (size_t)gridDim.x * blockDim.x;
  for (size_t i = (size_t)blockIdx.x * blockDim.x + threadIdx.x; i < n4; i += stride) {
    float4 f = ((const float4*)src)[i];
    if (ab) { f.x = fabsf(f.x); f.y = fabsf(f.y); f.z = fabsf(f.z); f.w = fabsf(f.w); }
    m = fmaxf(m, fmaxf(fmaxf(f.x, f.y), fmaxf(f.z, f.w)));
  }
  for (int off = 32; off; off >>= 1) m = fmaxf(m, __shfl_down(m, off));
  __shared__ float sm[4];
  if ((threadIdx.x & 63) == 0) sm[threadIdx.x >> 6] = m;
  __syncthreads();
  if (threadIdx.x == 0) {
    float r = fmaxf(fmaxf(sm[0], sm[1]), fmaxf(sm[2], sm[3]));
    atomicMax(&sclu[y], fenc(r));
  }
}

// weight quant -> i8 (-127..127) + per-output-channel column sums (for u8 shift fix)
__global__ __launch_bounds__(256)
void quant_w_i8_kernel(const float* __restrict__ w0, const float* __restrict__ w1,
                       const float* __restrict__ w2, const float* __restrict__ w3,
                       i8* __restrict__ dst, int* __restrict__ colsum,
                       const u32* __restrict__ sclu) {
  int y = blockIdx.y, row = blockIdx.x, tid = threadIdx.x;
  const float* src = (y == 0 ? w0 : y == 1 ? w1 : y == 2 ? w2 : w3) + (size_t)row * NDM;
  float s = fmaxf(fdec(sclu[3 + y]), QEPS) / 127.0f;
  float4 f = ((const float4*)src)[tid];
  int a = (int)fminf(fmaxf(rintf(f.x / s), -127.f), 127.f);
  int b = (int)fminf(fmaxf(rintf(f.y / s), -127.f), 127.f);
  int c = (int)fminf(fmaxf(rintf(f.z / s), -127.f), 127.f);
  int d = (int)fminf(fmaxf(rintf(f.w / s), -127.f), 127.f);
  ((int*)(dst + (size_t)y * NDM * NDM + (size_t)row * NDM))[tid] =
      (a & 255) | ((b & 255) << 8) | ((c & 255) << 16) | ((d & 255) << 24);
  int ssum = a + b + c + d;
  for (int off = 32; off; off >>= 1) ssum += __shfl_down(ssum, off);
  __shared__ int sm[4];
  if ((tid & 63) == 0) sm[tid >> 6] = ssum;
  __syncthreads();
  if (tid == 0) colsum[y * NDM + row] = sm[0] + sm[1] + sm[2] + sm[3];
}

// uint8 activation fake-quant -> shifted i8 (q-128); y selects source/slot/dst
__global__ void quant_a_kernel(const float* __restrict__ s0, const float* __restrict__ s1,
                               const float* __restrict__ s2, i8* __restrict__ dst,
                               const u32* __restrict__ sclu, int slot_base) {
  int y = blockIdx.y;
  const float* src = y == 0 ? s0 : y == 1 ? s1 : s2;
  i8* d = dst + (size_t)y * NM * NDM;
  float s = fmaxf(fdec(sclu[slot_base + y]), QEPS) / 255.0f;
  size_t n4 = (size_t)NM * NDM / 4;
  size_t stride = (size_t)gridDim.x * blockDim.x;
  for (size_t i = (size_t)blockIdx.x * blockDim.x + threadIdx.x; i < n4; i += stride) {
    float4 f = ((const float4*)src)[i];
    int a = (int)fminf(fmaxf(rintf(f.x / s), 0.f), 255.f) - 128;
    int b = (int)fminf(fmaxf(rintf(f.y / s), 0.f), 255.f) - 128;
    int c = (int)fminf(fmaxf(rintf(f.z / s), 0.f), 255.f) - 128;
    int e = (int)fminf(fmaxf(rintf(f.w / s), 0.f), 255.f) - 128;
    ((int*)d)[i] = (a & 255) | ((b & 255) << 8) | ((c & 255) << 16) | ((e & 255) << 24);
  }
}

// proj fp32 -> int8 with per-s scale; y=0..2 selects q/k/v
__global__ void qkv_i8_kernel(const float* __restrict__ projbase, i8* __restrict__ dstbase,
                              const float* __restrict__ scl) {
  int y = blockIdx.y;
  const float* src = projbase + (size_t)y * NM * NDM;
  i8* dst = dstbase + (size_t)y * NM * NDM;
  const float* sb = scl + 8 + y * 128;
  size_t n4 = (size_t)NM * NDM / 4;
  size_t stride = (size_t)gridDim.x * blockDim.x;
  for (size_t i = (size_t)blockIdx.x * blockDim.x + threadIdx.x; i < n4; i += stride) {
    int s_idx = (int)((i >> 8) & 127);
    float s = fmaxf(sb[s_idx], QEPS) / 127.0f;
    float4 f = ((const float4*)src)[i];
    int a = (int)fminf(fmaxf(rintf(f.x / s), -128.f), 127.f);
    int b = (int)fminf(fmaxf(rintf(f.y / s), -128.f), 127.f);
    int c = (int)fminf(fmaxf(rintf(f.z / s), -128.f), 127.f);
    int d = (int)fminf(fmaxf(rintf(f.w / s), -128.f), 127.f);
    ((int*)dst)[i] = (a & 255) | ((b & 255) << 8) | ((c & 255) << 16) | ((d & 255) << 24);
  }
}

// ---------------- GEMM: i8 MFMA, K=64/iter, m97 staging ----------------
constexpr int BM = 128, BN = 128, BK = 64;

template <bool PROJ>
__global__ __launch_bounds__(256)
void gemm_kernel(const i8* __restrict__ Abase, const i8* __restrict__ Wbase,
                 const int* __restrict__ colsum, const float* __restrict__ b0,
                 const float* __restrict__ b1, const float* __restrict__ b2,
                 float* __restrict__ Cbase, u32* __restrict__ sclu) {
  constexpr int K = NDM, N = NDM;
  const int z = PROJ ? blockIdx.z : 0;
  const i8* A = Abase + (size_t)z * NM * NDM;
  const i8* Wt = PROJ ? (Wbase + (size_t)z * NDM * NDM) : Wbase;
  const float* bias = PROJ ? (z == 0 ? b0 : z == 1 ? b1 : b2) : b0;
  float* C = PROJ ? (Cbase + (size_t)z * NM * NDM) : Cbase;
  const u32* slot_in = PROJ ? (sclu + z) : (sclu + 7);
  const u32* slot_w = PROJ ? (sclu + 3 + z) : (sclu + 6);
  const int* cs = colsum + (PROJ ? z : 3) * NDM;

  __shared__ __align__(16) i8 As[BM][BK];  // 8 KB, contiguous (global_load_lds dest)
  __shared__ __align__(16) i8 Bs[BN][BK];
  __shared__ float rmax2[2][BM];

  const int tid = threadIdx.x;
  const int lane = tid & 63, wave = tid >> 6;
  const int wm = (wave & 1) * 64, wn = (wave >> 1) * 64;
  const int r16 = lane & 15, quad = lane >> 4;
  const int bm = blockIdx.x * BM, bn = blockIdx.y * BN;

  i32x4 acc[4][4] = {};

  const int lrow = lane >> 2, lcol = (lane & 3) * 16;  // 16 rows per glds16, 64B rows
  for (int k0 = 0; k0 < K; k0 += BK) {
    __syncthreads();
#pragma unroll
    for (int p = 0; p < 2; p++) {
      int r = wave * 32 + p * 16;
      glds16(A + (size_t)(bm + r + lrow) * K + k0 + lcol, &As[r][0]);
      glds16(Wt + (size_t)(bn + r + lrow) * K + k0 + lcol, &Bs[r][0]);
    }
    __syncthreads();
    i32x4 af[4], bfr[4];
#pragma unroll
    for (int i = 0; i < 4; i++) af[i] = *(const i32x4*)(&As[wm + i * 16 + r16][quad * 16]);
#pragma unroll
    for (int j = 0; j < 4; j++) bfr[j] = *(const i32x4*)(&Bs[wn + j * 16 + r16][quad * 16]);
#pragma unroll
    for (int i = 0; i < 4; i++)
#pragma unroll
      for (int j = 0; j < 4; j++)
        acc[i][j] = __builtin_amdgcn_mfma_i32_16x16x64_i8(af[i], bfr[j], acc[i][j], 0, 0, 0);
  }

  float s_in = fmaxf(fdec(*slot_in), QEPS) / 255.0f;
  float s_w = fmaxf(fdec(*slot_w), QEPS) / 127.0f;
  float sc = s_in * s_w;

  float bq[4];
  int csj[4];
#pragma unroll
  for (int j = 0; j < 4; j++) {
    int gc = bn + wn + j * 16 + r16;
    bq[j] = rintf(bias[gc] / sc) * sc;
    csj[j] = cs[gc] << 7;  // +128 * colsum(W): undoes the x-128 input shift
  }
#pragma unroll
  for (int i = 0; i < 4; i++) {
#pragma unroll
    for (int r = 0; r < 4; r++) {
      int lr = wm + i * 16 + quad * 4 + r;
      int gr = bm + lr;
      float rm = 0.0f;
#pragma unroll
      for (int j = 0; j < 4; j++) {
        int gc = bn + wn + j * 16 + r16;
        float val = (float)(acc[i][j][r] + csj[j]) * sc + bq[j];
        C[(size_t)gr * N + gc] = val;
        if (PROJ) rm = fmaxf(rm, fabsf(val));
      }
      if (PROJ) {
#pragma unroll
        for (int off = 1; off < 16; off <<= 1) rm = fmaxf(rm, __shfl_xor(rm, off));
        if (r16 == 0) rmax2[wave >> 1][lr] = rm;
      }
    }
  }
  if (PROJ) {
    __syncthreads();
    if (tid < BM) {
      float m = fmaxf(rmax2[0][tid], rmax2[1][tid]);
      atomicMax((int*)&sclu[8 + z * 128 + tid], __float_as_int(m));  // m >= 0
    }
  }
}

// ---------------- attention ----------------
// Phase 1: QK^T + softmax, colmax atomics only (P is NOT materialized)
__global__ __launch_bounds__(256)
void attn_colmax_kernel(const i8* __restrict__ qi8, const i8* __restrict__ ki8,
                        const u64* __restrict__ mb, const float* __restrict__ scl,
                        u32* __restrict__ sclu) {
  const int bh = blockIdx.x, b = bh >> 4, h = bh & 15;
  const int tid = threadIdx.x, lane = tid & 63, wave = tid >> 6;
  const int r16 = lane & 15, quad = lane >> 4;

  __shared__ __align__(16) i8 Qs[NS][80];
  __shared__ __align__(16) i8 Ks[NS][80];
  __shared__ float sqv[NS], skv[NS];
  __shared__ float cmw[4][NS];

  {
    int row = tid >> 1, half = (tid & 1) * 32;
    const i8* qp = qi8 + (size_t)(b * NS + row) * NDM + h * NDK + half;
    const i8* kp = ki8 + (size_t)(b * NS + row) * NDM + h * NDK + half;
    *(int4*)&Qs[row][half] = *(const int4*)qp;
    *(int4*)&Qs[row][half + 16] = *(const int4*)(qp + 16);
    *(int4*)&Ks[row][half] = *(const int4*)kp;
    *(int4*)&Ks[row][half + 16] = *(const int4*)(kp + 16);
    if (tid < NS) {
      sqv[tid] = fmaxf(scl[8 + tid], QEPS) / 127.0f;
      skv[tid] = fmaxf(scl[8 + 128 + tid], QEPS) / 127.0f;
    }
  }
  __syncthreads();

  const int rowbase = wave * 32;
  i32x4 acc[2][8] = {};
#pragma unroll
  for (int mt = 0; mt < 2; mt++) {
    i32x4 a = *(const i32x4*)&Qs[rowbase + mt * 16 + r16][quad * 16];
#pragma unroll
    for (int nt = 0; nt < 8; nt++) {
      i32x4 bfrag = *(const i32x4*)&Ks[nt * 16 + r16][quad * 16];
      acc[mt][nt] = __builtin_amdgcn_mfma_i32_16x16x64_i8(a, bfrag, acc[mt][nt], 0, 0, 0);
    }
  }

  float skc[8], cm[8];
#pragma unroll
  for (int nt = 0; nt < 8; nt++) { skc[nt] = skv[nt * 16 + r16]; cm[nt] = 0.0f; }

#pragma unroll
  for (int mt = 0; mt < 2; mt++) {
#pragma unroll
    for (int r = 0; r < 4; r++) {
      int row = rowbase + mt * 16 + quad * 4 + r;
      float sq = sqv[row];
      const u64* mrow = mb + ((size_t)b * NS + row) * 2;
      u64 m0 = mrow[0], m1 = mrow[1];
      float vals[8];
      float mx = -INFINITY;
#pragma unroll
      for (int nt = 0; nt < 8; nt++) {
        float v = (float)acc[mt][nt][r] * (sq * skc[nt]) * 0.125f;
        u64 bits = nt < 4 ? m0 : m1;
        if (((bits >> ((nt * 16 + r16) & 63)) & 1ull) == 0) v = -1e9f;
        vals[nt] = v;
        mx = fmaxf(mx, v);
      }
#pragma unroll
      for (int off = 1; off < 16; off <<= 1) mx = fmaxf(mx, __shfl_xor(mx, off));
      float sum = 0.0f;
#pragma unroll
      for (int nt = 0; nt < 8; nt++) { vals[nt] = __expf(vals[nt] - mx); sum += vals[nt]; }
#pragma unroll
      for (int off = 1; off < 16; off <<= 1) sum += __shfl_xor(sum, off);
#pragma unroll
      for (int nt = 0; nt < 8; nt++) {
        float p = vals[nt] / sum;
        cm[nt] = fmaxf(cm[nt], p);
      }
    }
  }

#pragma unroll
  for (int nt = 0; nt < 8; nt++) {
    float c = cm[nt];
    c = fmaxf(c, __shfl_xor(c, 16));
    c = fmaxf(c, __shfl_xor(c, 32));
    if (quad == 0) cmw[wave][nt * 16 + r16] = c;
  }
  __syncthreads();
  if (tid < NS) {
    float c = fmaxf(fmaxf(cmw[0][tid], cmw[1][tid]), fmaxf(cmw[2][tid], cmw[3][tid]));
    atomicMax((int*)&sclu[392 + tid], __float_as_int(c));  // p >= 0
  }
}

// Phase 2: recompute QK^T + softmax (bitwise-identical to phase 1), quantize P with
// final colmax scales into LDS (one 64-col half at a time), then PV.
// Occupancy-tuned: Q fragments direct to registers (no LDS), Ps halved, 38.9 KB LDS
// -> 4 blocks/CU (vs 2 before).
__global__ __launch_bounds__(256, 4)
void attn_pv2_kernel(const i8* __restrict__ qi8, const i8* __restrict__ ki8,
                     const i8* __restrict__ vi8, const u64* __restrict__ mb,
                     const float* __restrict__ scl, float* __restrict__ xout,
                     u32* __restrict__ xmax_slot) {
  const int bh = blockIdx.x, b = bh >> 4, h = bh & 15;
  const int tid = threadIdx.x, lane = tid & 63, wave = tid >> 6;
  const int r16 = lane & 15, quad = lane >> 4;
  const int rowbase = wave * 32;

  union SU {
    i8 K[NS][80];                                   // 10.0 KB (QK^T phase)
    struct { u16 hi[64][72]; u16 lo[64][72]; } v;   // 18.4 KB (PV phase)
  };
  __shared__ __align__(16) SU u;
  __shared__ __align__(16) u16 Ps[NS][72];  // 18 KB; holds one 64-col half at a time
  __shared__ float sqv[NS], skv[NS], spv[NS], svv[NS];

  // Stage K cooperatively into LDS; Q A-fragments go straight to registers
  // (wave-private rows -> no sharing -> no LDS needed).
  i32x4 aq[2];
  {
    int row = tid >> 1, half = (tid & 1) * 32;
    const i8* kp = ki8 + (size_t)(b * NS + row) * NDM + h * NDK + half;
    *(int4*)&u.K[row][half] = *(const int4*)kp;
    *(int4*)&u.K[row][half + 16] = *(const int4*)(kp + 16);
    const i8* qp = qi8 + (size_t)b * NS * NDM + h * NDK;
#pragma unroll
    for (int mt = 0; mt < 2; mt++)
      aq[mt] = *(const i32x4*)(qp + (size_t)(rowbase + mt * 16 + r16) * NDM + quad * 16);
    if (tid < NS) {
      sqv[tid] = fmaxf(scl[8 + tid], QEPS) / 127.0f;
      skv[tid] = fmaxf(scl[8 + 128 + tid], QEPS) / 127.0f;
      spv[tid] = fmaxf(scl[392 + tid], QEPS) / 127.0f;
      svv[tid] = fmaxf(scl[8 + 256 + tid], QEPS) / 127.0f;
    }
  }
  __syncthreads();

  i32x4 acc[2][8] = {};
#pragma unroll
  for (int mt = 0; mt < 2; mt++) {
#pragma unroll
    for (int nt = 0; nt < 8; nt++) {
      i32x4 bfrag = *(const i32x4*)&u.K[nt * 16 + r16][quad * 16];
      acc[mt][nt] = __builtin_amdgcn_mfma_i32_16x16x64_i8(aq[mt], bfrag, acc[mt][nt], 0, 0, 0);
    }
  }

  float skc[8], spc[8];
#pragma unroll
  for (int nt = 0; nt < 8; nt++) {
    skc[nt] = skv[nt * 16 + r16];
    spc[nt] = spv[nt * 16 + r16];
  }

  // Softmax (bitwise-identical to phase 1). Low half (cols 0-63) -> Ps now;
  // high half (cols 64-127) -> packed bf16 in registers, written after PV half 0.
  // Ps is wave-local (each wave touches only its own 32 rows), so no barrier needed.
  u32 pqh[2][4][2];
#pragma unroll
  for (int mt = 0; mt < 2; mt++) {
#pragma unroll
    for (int r = 0; r < 4; r++) {
      int row = rowbase + mt * 16 + quad * 4 + r;
      float sq = sqv[row];
      const u64* mrow = mb + ((size_t)b * NS + row) * 2;
      u64 m0 = mrow[0], m1 = mrow[1];
      float vals[8];
      float mx = -INFINITY;
#pragma unroll
      for (int nt = 0; nt < 8; nt++) {
        float v = (float)acc[mt][nt][r] * (sq * skc[nt]) * 0.125f;
        u64 bits = nt < 4 ? m0 : m1;
        if (((bits >> ((nt * 16 + r16) & 63)) & 1ull) == 0) v = -1e9f;
        vals[nt] = v;
        mx = fmaxf(mx, v);
      }
#pragma unroll
      for (int off = 1; off < 16; off <<= 1) mx = fmaxf(mx, __shfl_xor(mx, off));
      float sum = 0.0f;
#pragma unroll
      for (int nt = 0; nt < 8; nt++) { vals[nt] = __expf(vals[nt] - mx); sum += vals[nt]; }
#pragma unroll
      for (int off = 1; off < 16; off <<= 1) sum += __shfl_xor(sum, off);
#pragma unroll
      for (int nt = 0; nt < 4; nt++) {
        float p = vals[nt] / sum;  // bitwise equal to phase-1 p
        float pq = fminf(fmaxf(rintf(p / spc[nt]), -128.f), 127.f);
        Ps[row][nt * 16 + r16] = f2bf(pq);  // small ints: exact in bf16
      }
#pragma unroll
      for (int n2 = 0; n2 < 2; n2++) {
        float pa_ = vals[4 + n2 * 2] / sum;
        float pb_ = vals[5 + n2 * 2] / sum;
        float qa = fminf(fmaxf(rintf(pa_ / spc[4 + n2 * 2]), -128.f), 127.f);
        float qb = fminf(fmaxf(rintf(pb_ / spc[5 + n2 * 2]), -128.f), 127.f);
        pqh[mt][r][n2] = (u32)f2bf(qa) | ((u32)f2bf(qb) << 16);
      }
    }
  }

  f32x4 xacc[2][4] = {};
#pragma unroll
  for (int half = 0; half < 2; half++) {
    __syncthreads();  // half0: all waves done reading u.K; half1: done reading V half0
    {
      int jl = tid >> 2, d0 = (tid & 3) * 16;
      int j = half * 64 + jl;
      float g = spv[j] * svv[j];
      const i8* vp = vi8 + (size_t)(b * NS + j) * NDM + h * NDK + d0;
      int4 raw = *(const int4*)vp;
      const i8* rb = (const i8*)&raw;
#pragma unroll
      for (int d = 0; d < 16; d++) {
        float w = (float)rb[d] * g;
        u16 hi = f2bf(w);
        u.v.hi[d0 + d][jl] = hi;
        u.v.lo[d0 + d][jl] = f2bf(w - bf2f(hi));
      }
    }
    __syncthreads();
#pragma unroll
    for (int kk = 0; kk < 2; kk++) {
      short8 pa[2];
#pragma unroll
      for (int mt = 0; mt < 2; mt++)
        pa[mt] = *(const short8*)&Ps[rowbase + mt * 16 + r16][kk * 32 + quad * 8];
#pragma unroll
      for (int nt = 0; nt < 4; nt++) {
        short8 vh = *(const short8*)&u.v.hi[nt * 16 + r16][kk * 32 + quad * 8];
        short8 vl = *(const short8*)&u.v.lo[nt * 16 + r16][kk * 32 + quad * 8];
#pragma unroll
        for (int mt = 0; mt < 2; mt++) {
          xacc[mt][nt] = __builtin_amdgcn_mfma_f32_16x16x32_bf16(pa[mt], vh, xacc[mt][nt], 0, 0, 0);
          xacc[mt][nt] = __builtin_amdgcn_mfma_f32_16x16x32_bf16(pa[mt], vl, xacc[mt][nt], 0, 0, 0);
        }
      }
    }
    if (half == 0) {
      // Overwrite Ps with cols 64-127 (wave-local rows; own reads above are done
      // in program order, other waves never touch these rows).
#pragma unroll
      for (int mt = 0; mt < 2; mt++)
#pragma unroll
        for (int r = 0; r < 4; r++) {
          int row = rowbase + mt * 16 + quad * 4 + r;
#pragma unroll
          for (int n2 = 0; n2 < 2; n2++) {
            u32 pk = pqh[mt][r][n2];
            Ps[row][(n2 * 2) * 16 + r16] = (u16)(pk & 0xFFFFu);
            Ps[row][(n2 * 2 + 1) * 16 + r16] = (u16)(pk >> 16);
          }
        }
    }
  }

  float mx = -INFINITY;
#pragma unroll
  for (int mt = 0; mt < 2; mt++)
#pragma unroll
    for (int nt = 0; nt < 4; nt++)
#pragma unroll
      for (int r = 0; r < 4; r++) {
        int row = rowbase + mt * 16 + quad * 4 + r;
        xout[((size_t)b * NS + row) * NDM + h * NDK + nt * 16 + r16] = xacc[mt][nt][r];
        mx = fmaxf(mx, xacc[mt][nt][r]);
      }
#pragma unroll
  for (int off = 1; off < 64; off <<= 1) mx = fmaxf(mx, __shfl_xor(mx, off));
  if (lane == 0) atomicMax(xmax_slot, fenc(mx));
}

// ---------------- workspace layout ----------------
constexpr size_t OFF_SCL = 0;                                   // 8 KB (2048 u32)
constexpr size_t OFF_CS  = 8192;                                // colsum 4x1024 int = 16 KB
constexpr size_t OFF_MB  = OFF_CS + 4 * NDM * 4;                // mask bits 128 KB
constexpr size_t OFF_W   = OFF_MB + (size_t)NM * 16;            // i8 weights 4 MB
constexpr size_t OFF_XQ  = OFF_W + 4 * (size_t)NDM * NDM;       // i8 acts 3x8 MB
constexpr size_t OFF_PQ  = OFF_XQ + 3 * (size_t)NM * NDM;       // f32 proj 3x33.5 MB
constexpr size_t OFF_I8  = OFF_PQ + 3 * (size_t)NM * NDM * 4;   // attn i8 qkv 3x8 MB
// xout aliases projv (dead after qkv_i8); P is never materialized (flash recompute)

extern "C" void kernel_launch(void* const* d_in, const int* in_sizes, int n_in,
                              void* d_out, int out_size, void* d_ws, size_t ws_size,
                              hipStream_t stream) {
  const float* query = (const float*)d_in[0];
  const float* key = (const float*)d_in[1];
  const float* value = (const float*)d_in[2];
  const int* mask = (const int*)d_in[3];
  const float* Wq = (const float*)d_in[4]; const float* bq = (const float*)d_in[5];
  const float* Wk = (const float*)d_in[6]; const float* bk = (const float*)d_in[7];
  const float* Wv = (const float*)d_in[8]; const float* bv = (const float*)d_in[9];
  const float* Wo = (const float*)d_in[10]; const float* bo = (const float*)d_in[11];

  char* ws = (char*)d_ws;
  float* scl = (float*)(ws + OFF_SCL);
  u32* sclu = (u32*)scl;
  int* colsum = (int*)(ws + OFF_CS);
  u64* mb = (u64*)(ws + OFF_MB);
  i8* wb = (i8*)(ws + OFF_W);        // wq|wk|wv|wo
  i8* wob = wb + 3 * (size_t)NDM * NDM;
  i8* xq = (i8*)(ws + OFF_XQ);       // q|k|v shifted i8 (slot 0 reused for x)
  float* proj = (float*)(ws + OFF_PQ);
  i8* qkv8 = (i8*)(ws + OFF_I8);
  float* xout = proj + 2 * (size_t)NM * NDM;
  i8* vi8 = qkv8 + 2 * (size_t)NM * NDM;

  maskbits_kernel<<<NM / 4, 256, 0, stream>>>(mask, mb, sclu);
  fused_max_kernel<<<dim3(512, 7), 256, 0, stream>>>(query, key, value, Wq, Wk, Wv, Wo, sclu);
  quant_w_i8_kernel<<<dim3(NDM, 4), 256, 0, stream>>>(Wq, Wk, Wv, Wo, wb, colsum, sclu);
  quant_a_kernel<<<dim3(512, 3), 256, 0, stream>>>(query, key, value, xq, sclu, 0);

  gemm_kernel<true><<<dim3(NM / BM, NDM / BN, 3), 256, 0, stream>>>(
      xq, wb, colsum, bq, bk, bv, proj, sclu);

  qkv_i8_kernel<<<dim3(512, 3), 256, 0, stream>>>(proj, qkv8, scl);

  attn_colmax_kernel<<<NB * NH, 256, 0, stream>>>(qkv8, qkv8 + (size_t)NM * NDM, mb, scl,
                                                  sclu);
  attn_pv2_kernel<<<NB * NH, 256, 0, stream>>>(qkv8, qkv8 + (size_t)NM * NDM, vi8, mb, scl,
                                               xout, sclu + 7);

  quant_a_kernel<<<dim3(512, 1), 256, 0, stream>>>(xout, xout, xout, xq, sclu, 7);
  gemm_kernel<false><<<dim3(NM / BM, NDM / BN, 1), 256, 0, stream>>>(
      xq, wob, colsum, bo, bo, bo, (float*)d_out, sclu);
}

// Round 6
// 388.494 us; speedup vs baseline: 1.1196x; 1.0898x over previous
//
#include <hip/hip_runtime.h>
#include <hip/hip_bf16.h>
#include <math.h>

typedef unsigned short u16;
typedef unsigned int u32;
typedef unsigned long long u64;
typedef signed char i8;

constexpr int NB = 64, NS = 128, NDM = 1024, NH = 16, NDK = 64;
constexpr int NM = NB * NS;  // 8192
constexpr float QEPS = 1e-8f;

typedef __attribute__((ext_vector_type(8))) short short8;
typedef __attribute__((ext_vector_type(4))) float f32x4;
typedef __attribute__((ext_vector_type(4))) int i32x4;

__device__ __forceinline__ u32 fenc(float f) {
  u32 u = __float_as_uint(f);
  return (u & 0x80000000u) ? ~u : (u | 0x80000000u);
}
__device__ __forceinline__ float fdec(u32 u) {
  u = (u & 0x80000000u) ? (u & 0x7FFFFFFFu) : ~u;
  return __uint_as_float(u);
}
// quantized values are small integers -> exact bf16 truncation
__device__ __forceinline__ u16 f2bf(float f) { return (u16)(__float_as_uint(f) >> 16); }
__device__ __forceinline__ float bf2f(u16 u) { return __uint_as_float(((u32)u) << 16); }

// async global->LDS, 16B per lane; lds dest = wave-uniform base + lane*16
__device__ __forceinline__ void glds16(const void* g, void* l) {
  __builtin_amdgcn_global_load_lds(
      (const __attribute__((address_space(1))) void*)(unsigned long long)(uintptr_t)g,
      (__attribute__((address_space(3))) void*)(u32)(uintptr_t)l, 16, 0, 0);
}

// ---- scale slots (u32/float at ws offset 0) ----
// [0..2] enc max(q,k,v)  [3..6] enc absmax(W*)  [7] enc max(x)
// [8..135] absmax_q per s; [136..263] absmax_k; [264..391] absmax_v (plain float bits)
// [392..519] colmax_p per j (plain float bits)

// mask[B,S,S] int32 -> bitmask [B*S][2] u64; block 0 also zeroes the scale slots
__global__ void maskbits_kernel(const int* __restrict__ mask, u64* __restrict__ mb,
                                u32* __restrict__ scl) {
  if (blockIdx.x == 0) {
    for (int i = threadIdx.x; i < 2048; i += blockDim.x) scl[i] = 0u;
  }
  int row = blockIdx.x * 4 + (threadIdx.x >> 6);
  int lane = threadIdx.x & 63;
  const int* mrow = mask + (size_t)row * NS;
  u64 b0 = __ballot(mrow[lane] != 0);
  u64 b1 = __ballot(mrow[64 + lane] != 0);
  if (lane == 0) { mb[row * 2] = b0; mb[row * 2 + 1] = b1; }
}

// fused 7-way max reduce: y=0..2 max(q,k,v); y=3..6 absmax(Wq..Wo)
__global__ void fused_max_kernel(const float* __restrict__ q, const float* __restrict__ k,
                                 const float* __restrict__ v, const float* __restrict__ w0,
                                 const float* __restrict__ w1, const float* __restrict__ w2,
                                 const float* __restrict__ w3, u32* __restrict__ sclu) {
  int y = blockIdx.y;
  const float* src; size_t n4; int ab;
  switch (y) {
    case 0: src = q; n4 = (size_t)NM * NDM / 4; ab = 0; break;
    case 1: src = k; n4 = (size_t)NM * NDM / 4; ab = 0; break;
    case 2: src = v; n4 = (size_t)NM * NDM / 4; ab = 0; break;
    case 3: src = w0; n4 = (size_t)NDM * NDM / 4; ab = 1; break;
    case 4: src = w1; n4 = (size_t)NDM * NDM / 4; ab = 1; break;
    case 5: src = w2; n4 = (size_t)NDM * NDM / 4; ab = 1; break;
    default: src = w3; n4 = (size_t)NDM * NDM / 4; ab = 1; break;
  }
  float m = -INFINITY;
  size_t stride = (size_t)gridDim.x * blockDim.x;
  for (size_t i = (size_t)blockIdx.x * blockDim.x + threadIdx.x; i < n4; i += stride) {
    float4 f = ((const float4*)src)[i];
    if (ab) { f.x = fabsf(f.x); f.y = fabsf(f.y); f.z = fabsf(f.z); f.w = fabsf(f.w); }
    m = fmaxf(m, fmaxf(fmaxf(f.x, f.y), fmaxf(f.z, f.w)));
  }
  for (int off = 32; off; off >>= 1) m = fmaxf(m, __shfl_down(m, off));
  __shared__ float sm[4];
  if ((threadIdx.x & 63) == 0) sm[threadIdx.x >> 6] = m;
  __syncthreads();
  if (threadIdx.x == 0) {
    float r = fmaxf(fmaxf(sm[0], sm[1]), fmaxf(sm[2], sm[3]));
    atomicMax(&sclu[y], fenc(r));
  }
}

// weight quant -> i8 (-127..127) + per-output-channel column sums (for u8 shift fix)
__global__ __launch_bounds__(256)
void quant_w_i8_kernel(const float* __restrict__ w0, const float* __restrict__ w1,
                       const float* __restrict__ w2, const float* __restrict__ w3,
                       i8* __restrict__ dst, int* __restrict__ colsum,
                       const u32* __restrict__ sclu) {
  int y = blockIdx.y, row = blockIdx.x, tid = threadIdx.x;
  const float* src = (y == 0 ? w0 : y == 1 ? w1 : y == 2 ? w2 : w3) + (size_t)row * NDM;
  float s = fmaxf(fdec(sclu[3 + y]), QEPS) / 127.0f;
  float4 f = ((const float4*)src)[tid];
  int a = (int)fminf(fmaxf(rintf(f.x / s), -127.f), 127.f);
  int b = (int)fminf(fmaxf(rintf(f.y / s), -127.f), 127.f);
  int c = (int)fminf(fmaxf(rintf(f.z / s), -127.f), 127.f);
  int d = (int)fminf(fmaxf(rintf(f.w / s), -127.f), 127.f);
  ((int*)(dst + (size_t)y * NDM * NDM + (size_t)row * NDM))[tid] =
      (a & 255) | ((b & 255) << 8) | ((c & 255) << 16) | ((d & 255) << 24);
  int ssum = a + b + c + d;
  for (int off = 32; off; off >>= 1) ssum += __shfl_down(ssum, off);
  __shared__ int sm[4];
  if ((tid & 63) == 0) sm[tid >> 6] = ssum;
  __syncthreads();
  if (tid == 0) colsum[y * NDM + row] = sm[0] + sm[1] + sm[2] + sm[3];
}

// uint8 activation fake-quant -> shifted i8 (q-128); y selects source/slot/dst
__global__ void quant_a_kernel(const float* __restrict__ s0, const float* __restrict__ s1,
                               const float* __restrict__ s2, i8* __restrict__ dst,
                               const u32* __restrict__ sclu, int slot_base) {
  int y = blockIdx.y;
  const float* src = y == 0 ? s0 : y == 1 ? s1 : s2;
  i8* d = dst + (size_t)y * NM * NDM;
  float s = fmaxf(fdec(sclu[slot_base + y]), QEPS) / 255.0f;
  size_t n4 = (size_t)NM * NDM / 4;
  size_t stride = (size_t)gridDim.x * blockDim.x;
  for (size_t i = (size_t)blockIdx.x * blockDim.x + threadIdx.x; i < n4; i += stride) {
    float4 f = ((const float4*)src)[i];
    int a = (int)fminf(fmaxf(rintf(f.x / s), 0.f), 255.f) - 128;
    int b = (int)fminf(fmaxf(rintf(f.y / s), 0.f), 255.f) - 128;
    int c = (int)fminf(fmaxf(rintf(f.z / s), 0.f), 255.f) - 128;
    int e = (int)fminf(fmaxf(rintf(f.w / s), 0.f), 255.f) - 128;
    ((int*)d)[i] = (a & 255) | ((b & 255) << 8) | ((c & 255) << 16) | ((e & 255) << 24);
  }
}

// proj fp32 -> int8 with per-s scale; y=0..2 selects q/k/v
__global__ void qkv_i8_kernel(const float* __restrict__ projbase, i8* __restrict__ dstbase,
                              const float* __restrict__ scl) {
  int y = blockIdx.y;
  const float* src = projbase + (size_t)y * NM * NDM;
  i8* dst = dstbase + (size_t)y * NM * NDM;
  const float* sb = scl + 8 + y * 128;
  size_t n4 = (size_t)NM * NDM / 4;
  size_t stride = (size_t)gridDim.x * blockDim.x;
  for (size_t i = (size_t)blockIdx.x * blockDim.x + threadIdx.x; i < n4; i += stride) {
    int s_idx = (int)((i >> 8) & 127);
    float s = fmaxf(sb[s_idx], QEPS) / 127.0f;
    float4 f = ((const float4*)src)[i];
    int a = (int)fminf(fmaxf(rintf(f.x / s), -128.f), 127.f);
    int b = (int)fminf(fmaxf(rintf(f.y / s), -128.f), 127.f);
    int c = (int)fminf(fmaxf(rintf(f.z / s), -128.f), 127.f);
    int d = (int)fminf(fmaxf(rintf(f.w / s), -128.f), 127.f);
    ((int*)dst)[i] = (a & 255) | ((b & 255) << 8) | ((c & 255) << 16) | ((d & 255) << 24);
  }
}

// ---------------- GEMM: i8 MFMA, K=64/iter, m97 staging ----------------
constexpr int BM = 128, BN = 128, BK = 64;

template <bool PROJ>
__global__ __launch_bounds__(256)
void gemm_kernel(const i8* __restrict__ Abase, const i8* __restrict__ Wbase,
                 const int* __restrict__ colsum, const float* __restrict__ b0,
                 const float* __restrict__ b1, const float* __restrict__ b2,
                 float* __restrict__ Cbase, u32* __restrict__ sclu) {
  constexpr int K = NDM, N = NDM;
  const int z = PROJ ? blockIdx.z : 0;
  const i8* A = Abase + (size_t)z * NM * NDM;
  const i8* Wt = PROJ ? (Wbase + (size_t)z * NDM * NDM) : Wbase;
  const float* bias = PROJ ? (z == 0 ? b0 : z == 1 ? b1 : b2) : b0;
  float* C = PROJ ? (Cbase + (size_t)z * NM * NDM) : Cbase;
  const u32* slot_in = PROJ ? (sclu + z) : (sclu + 7);
  const u32* slot_w = PROJ ? (sclu + 3 + z) : (sclu + 6);
  const int* cs = colsum + (PROJ ? z : 3) * NDM;

  __shared__ __align__(16) i8 As[BM][BK];  // 8 KB, contiguous (global_load_lds dest)
  __shared__ __align__(16) i8 Bs[BN][BK];
  __shared__ float rmax2[2][BM];

  const int tid = threadIdx.x;
  const int lane = tid & 63, wave = tid >> 6;
  const int wm = (wave & 1) * 64, wn = (wave >> 1) * 64;
  const int r16 = lane & 15, quad = lane >> 4;
  const int bm = blockIdx.x * BM, bn = blockIdx.y * BN;

  i32x4 acc[4][4] = {};

  const int lrow = lane >> 2, lcol = (lane & 3) * 16;  // 16 rows per glds16, 64B rows
  for (int k0 = 0; k0 < K; k0 += BK) {
    __syncthreads();
#pragma unroll
    for (int p = 0; p < 2; p++) {
      int r = wave * 32 + p * 16;
      glds16(A + (size_t)(bm + r + lrow) * K + k0 + lcol, &As[r][0]);
      glds16(Wt + (size_t)(bn + r + lrow) * K + k0 + lcol, &Bs[r][0]);
    }
    __syncthreads();
    i32x4 af[4], bfr[4];
#pragma unroll
    for (int i = 0; i < 4; i++) af[i] = *(const i32x4*)(&As[wm + i * 16 + r16][quad * 16]);
#pragma unroll
    for (int j = 0; j < 4; j++) bfr[j] = *(const i32x4*)(&Bs[wn + j * 16 + r16][quad * 16]);
#pragma unroll
    for (int i = 0; i < 4; i++)
#pragma unroll
      for (int j = 0; j < 4; j++)
        acc[i][j] = __builtin_amdgcn_mfma_i32_16x16x64_i8(af[i], bfr[j], acc[i][j], 0, 0, 0);
  }

  float s_in = fmaxf(fdec(*slot_in), QEPS) / 255.0f;
  float s_w = fmaxf(fdec(*slot_w), QEPS) / 127.0f;
  float sc = s_in * s_w;

  float bq[4];
  int csj[4];
#pragma unroll
  for (int j = 0; j < 4; j++) {
    int gc = bn + wn + j * 16 + r16;
    bq[j] = rintf(bias[gc] / sc) * sc;
    csj[j] = cs[gc] << 7;  // +128 * colsum(W): undoes the x-128 input shift
  }
#pragma unroll
  for (int i = 0; i < 4; i++) {
#pragma unroll
    for (int r = 0; r < 4; r++) {
      int lr = wm + i * 16 + quad * 4 + r;
      int gr = bm + lr;
      float rm = 0.0f;
#pragma unroll
      for (int j = 0; j < 4; j++) {
        int gc = bn + wn + j * 16 + r16;
        float val = (float)(acc[i][j][r] + csj[j]) * sc + bq[j];
        C[(size_t)gr * N + gc] = val;
        if (PROJ) rm = fmaxf(rm, fabsf(val));
      }
      if (PROJ) {
#pragma unroll
        for (int off = 1; off < 16; off <<= 1) rm = fmaxf(rm, __shfl_xor(rm, off));
        if (r16 == 0) rmax2[wave >> 1][lr] = rm;
      }
    }
  }
  if (PROJ) {
    __syncthreads();
    if (tid < BM) {
      float m = fmaxf(rmax2[0][tid], rmax2[1][tid]);
      atomicMax((int*)&sclu[8 + z * 128 + tid], __float_as_int(m));  // m >= 0
    }
  }
}

// ---------------- attention ----------------
// Phase 1: QK^T + softmax; per-block colmax vector -> scratch (NO atomics; a tiny
// reduce kernel computes the identical per-j max afterwards)
__global__ __launch_bounds__(256)
void attn_colmax_kernel(const i8* __restrict__ qi8, const i8* __restrict__ ki8,
                        const u64* __restrict__ mb, const float* __restrict__ scl,
                        float* __restrict__ cm_part) {
  const int bh = blockIdx.x, b = bh >> 4, h = bh & 15;
  const int tid = threadIdx.x, lane = tid & 63, wave = tid >> 6;
  const int r16 = lane & 15, quad = lane >> 4;

  __shared__ __align__(16) i8 Qs[NS][80];
  __shared__ __align__(16) i8 Ks[NS][80];
  __shared__ float sqv[NS], skv[NS];
  __shared__ float cmw[4][NS];

  {
    int row = tid >> 1, half = (tid & 1) * 32;
    const i8* qp = qi8 + (size_t)(b * NS + row) * NDM + h * NDK + half;
    const i8* kp = ki8 + (size_t)(b * NS + row) * NDM + h * NDK + half;
    *(int4*)&Qs[row][half] = *(const int4*)qp;
    *(int4*)&Qs[row][half + 16] = *(const int4*)(qp + 16);
    *(int4*)&Ks[row][half] = *(const int4*)kp;
    *(int4*)&Ks[row][half + 16] = *(const int4*)(kp + 16);
    if (tid < NS) {
      sqv[tid] = fmaxf(scl[8 + tid], QEPS) / 127.0f;
      skv[tid] = fmaxf(scl[8 + 128 + tid], QEPS) / 127.0f;
    }
  }
  __syncthreads();

  const int rowbase = wave * 32;
  i32x4 acc[2][8] = {};
#pragma unroll
  for (int mt = 0; mt < 2; mt++) {
    i32x4 a = *(const i32x4*)&Qs[rowbase + mt * 16 + r16][quad * 16];
#pragma unroll
    for (int nt = 0; nt < 8; nt++) {
      i32x4 bfrag = *(const i32x4*)&Ks[nt * 16 + r16][quad * 16];
      acc[mt][nt] = __builtin_amdgcn_mfma_i32_16x16x64_i8(a, bfrag, acc[mt][nt], 0, 0, 0);
    }
  }

  float skc[8], cm[8];
#pragma unroll
  for (int nt = 0; nt < 8; nt++) { skc[nt] = skv[nt * 16 + r16]; cm[nt] = 0.0f; }

#pragma unroll
  for (int mt = 0; mt < 2; mt++) {
#pragma unroll
    for (int r = 0; r < 4; r++) {
      int row = rowbase + mt * 16 + quad * 4 + r;
      float sq = sqv[row];
      const u64* mrow = mb + ((size_t)b * NS + row) * 2;
      u64 m0 = mrow[0], m1 = mrow[1];
      float vals[8];
      float mx = -INFINITY;
#pragma unroll
      for (int nt = 0; nt < 8; nt++) {
        float v = (float)acc[mt][nt][r] * (sq * skc[nt]) * 0.125f;
        u64 bits = nt < 4 ? m0 : m1;
        if (((bits >> ((nt * 16 + r16) & 63)) & 1ull) == 0) v = -1e9f;
        vals[nt] = v;
        mx = fmaxf(mx, v);
      }
#pragma unroll
      for (int off = 1; off < 16; off <<= 1) mx = fmaxf(mx, __shfl_xor(mx, off));
      float sum = 0.0f;
#pragma unroll
      for (int nt = 0; nt < 8; nt++) { vals[nt] = __expf(vals[nt] - mx); sum += vals[nt]; }
#pragma unroll
      for (int off = 1; off < 16; off <<= 1) sum += __shfl_xor(sum, off);
#pragma unroll
      for (int nt = 0; nt < 8; nt++) {
        float p = vals[nt] / sum;
        cm[nt] = fmaxf(cm[nt], p);
      }
    }
  }

#pragma unroll
  for (int nt = 0; nt < 8; nt++) {
    float c = cm[nt];
    c = fmaxf(c, __shfl_xor(c, 16));
    c = fmaxf(c, __shfl_xor(c, 32));
    if (quad == 0) cmw[wave][nt * 16 + r16] = c;
  }
  __syncthreads();
  if (tid < NS) {
    float c = fmaxf(fmaxf(cmw[0][tid], cmw[1][tid]), fmaxf(cmw[2][tid], cmw[3][tid]));
    cm_part[(size_t)tid * (NB * NH) + bh] = c;  // [j][bh] layout, plain store
  }
}

// cm_part[j][0..1023] -> scl[392+j] = max (identical value set as the old atomics)
__global__ void colmax_reduce_kernel(const float* __restrict__ cm_part,
                                     u32* __restrict__ sclu) {
  int j = blockIdx.x;
  const float* row = cm_part + (size_t)j * (NB * NH);
  float m = 0.0f;
  for (int i = threadIdx.x; i < NB * NH; i += blockDim.x) m = fmaxf(m, row[i]);
  for (int off = 32; off; off >>= 1) m = fmaxf(m, __shfl_down(m, off));
  __shared__ float sm[4];
  if ((threadIdx.x & 63) == 0) sm[threadIdx.x >> 6] = m;
  __syncthreads();
  if (threadIdx.x == 0)
    sclu[392 + j] = __float_as_uint(fmaxf(fmaxf(sm[0], sm[1]), fmaxf(sm[2], sm[3])));
}

// Phase 2: recompute QK^T + softmax (bitwise-identical to phase 1), quantize P with
// final colmax scales into LDS (one 64-col half at a time), then PV.
// This round: V prefetched to regs at entry (T14), K staged via global_load_lds
// (packed [128][64]), setprio around MFMA, ONE xmax atomic per block.
__global__ __launch_bounds__(256, 4)
void attn_pv2_kernel(const i8* __restrict__ qi8, const i8* __restrict__ ki8,
                     const i8* __restrict__ vi8, const u64* __restrict__ mb,
                     const float* __restrict__ scl, float* __restrict__ xout,
                     u32* __restrict__ xmax_slot) {
  const int bh = blockIdx.x, b = bh >> 4, h = bh & 15;
  const int tid = threadIdx.x, lane = tid & 63, wave = tid >> 6;
  const int r16 = lane & 15, quad = lane >> 4;
  const int rowbase = wave * 32;

  union SU {
    i8 K[NS][64];                                   // 8 KB packed (global_load_lds dest)
    struct { u16 hi[64][72]; u16 lo[64][72]; } v;   // 18.4 KB (PV phase)
  };
  __shared__ __align__(16) SU u;
  __shared__ __align__(16) u16 Ps[NS][72];  // 18 KB; holds one 64-col half at a time
  __shared__ float sqv[NS], skv[NS], spv[NS], svv[NS];
  __shared__ float xmw[4];

  // --- issue ALL global loads up front: V (both halves), Q frags, K via glds16 ---
  const int jl = tid >> 2, d0v = (tid & 3) * 16;
  const i8* vb = vi8 + (size_t)(b * NS + jl) * NDM + h * NDK + d0v;
  int4 vpre0 = *(const int4*)vb;                        // V rows 0..63
  int4 vpre1 = *(const int4*)(vb + (size_t)64 * NDM);   // V rows 64..127

  i32x4 aq[2];
  {
    const i8* qp = qi8 + (size_t)b * NS * NDM + h * NDK;
#pragma unroll
    for (int mt = 0; mt < 2; mt++)
      aq[mt] = *(const i32x4*)(qp + (size_t)(rowbase + mt * 16 + r16) * NDM + quad * 16);
    const int lrow = lane >> 2, lcol = (lane & 3) * 16;
#pragma unroll
    for (int p = 0; p < 2; p++) {
      int r = wave * 32 + p * 16;
      glds16(ki8 + (size_t)(b * NS + r + lrow) * NDM + h * NDK + lcol, &u.K[r][0]);
    }
    if (tid < NS) {
      sqv[tid] = fmaxf(scl[8 + tid], QEPS) / 127.0f;
      skv[tid] = fmaxf(scl[8 + 128 + tid], QEPS) / 127.0f;
      spv[tid] = fmaxf(scl[392 + tid], QEPS) / 127.0f;
      svv[tid] = fmaxf(scl[8 + 256 + tid], QEPS) / 127.0f;
    }
  }
  __syncthreads();

  i32x4 acc[2][8] = {};
  __builtin_amdgcn_s_setprio(1);
#pragma unroll
  for (int mt = 0; mt < 2; mt++) {
#pragma unroll
    for (int nt = 0; nt < 8; nt++) {
      i32x4 bfrag = *(const i32x4*)&u.K[nt * 16 + r16][quad * 16];
      acc[mt][nt] = __builtin_amdgcn_mfma_i32_16x16x64_i8(aq[mt], bfrag, acc[mt][nt], 0, 0, 0);
    }
  }
  __builtin_amdgcn_s_setprio(0);

  float skc[8], spc[8];
#pragma unroll
  for (int nt = 0; nt < 8; nt++) {
    skc[nt] = skv[nt * 16 + r16];
    spc[nt] = spv[nt * 16 + r16];
  }

  // Softmax (bitwise-identical to phase 1). Low half (cols 0-63) -> Ps now;
  // high half (cols 64-127) -> packed bf16 in registers, written after PV half 0.
  // Ps is wave-local (each wave touches only its own 32 rows), so no barrier needed.
  u32 pqh[2][4][2];
#pragma unroll
  for (int mt = 0; mt < 2; mt++) {
#pragma unroll
    for (int r = 0; r < 4; r++) {
      int row = rowbase + mt * 16 + quad * 4 + r;
      float sq = sqv[row];
      const u64* mrow = mb + ((size_t)b * NS + row) * 2;
      u64 m0 = mrow[0], m1 = mrow[1];
      float vals[8];
      float mx = -INFINITY;
#pragma unroll
      for (int nt = 0; nt < 8; nt++) {
        float v = (float)acc[mt][nt][r] * (sq * skc[nt]) * 0.125f;
        u64 bits = nt < 4 ? m0 : m1;
        if (((bits >> ((nt * 16 + r16) & 63)) & 1ull) == 0) v = -1e9f;
        vals[nt] = v;
        mx = fmaxf(mx, v);
      }
#pragma unroll
      for (int off = 1; off < 16; off <<= 1) mx = fmaxf(mx, __shfl_xor(mx, off));
      float sum = 0.0f;
#pragma unroll
      for (int nt = 0; nt < 8; nt++) { vals[nt] = __expf(vals[nt] - mx); sum += vals[nt]; }
#pragma unroll
      for (int off = 1; off < 16; off <<= 1) sum += __shfl_xor(sum, off);
#pragma unroll
      for (int nt = 0; nt < 4; nt++) {
        float p = vals[nt] / sum;  // bitwise equal to phase-1 p
        float pq = fminf(fmaxf(rintf(p / spc[nt]), -128.f), 127.f);
        Ps[row][nt * 16 + r16] = f2bf(pq);  // small ints: exact in bf16
      }
#pragma unroll
      for (int n2 = 0; n2 < 2; n2++) {
        float pa_ = vals[4 + n2 * 2] / sum;
        float pb_ = vals[5 + n2 * 2] / sum;
        float qa = fminf(fmaxf(rintf(pa_ / spc[4 + n2 * 2]), -128.f), 127.f);
        float qb = fminf(fmaxf(rintf(pb_ / spc[5 + n2 * 2]), -128.f), 127.f);
        pqh[mt][r][n2] = (u32)f2bf(qa) | ((u32)f2bf(qb) << 16);
      }
    }
  }

  f32x4 xacc[2][4] = {};
#pragma unroll
  for (int half = 0; half < 2; half++) {
    __syncthreads();  // half0: all waves done reading u.K; half1: done reading V half0
    {
      int j = half * 64 + jl;
      float g = spv[j] * svv[j];
      int4 raw = half ? vpre1 : vpre0;  // prefetched at entry; latency already hidden
      const i8* rb = (const i8*)&raw;
#pragma unroll
      for (int d = 0; d < 16; d++) {
        float w = (float)rb[d] * g;
        u16 hi = f2bf(w);
        u.v.hi[d0v + d][jl] = hi;
        u.v.lo[d0v + d][jl] = f2bf(w - bf2f(hi));
      }
    }
    __syncthreads();
    __builtin_amdgcn_s_setprio(1);
#pragma unroll
    for (int kk = 0; kk < 2; kk++) {
      short8 pa[2];
#pragma unroll
      for (int mt = 0; mt < 2; mt++)
        pa[mt] = *(const short8*)&Ps[rowbase + mt * 16 + r16][kk * 32 + quad * 8];
#pragma unroll
      for (int nt = 0; nt < 4; nt++) {
        short8 vh = *(const short8*)&u.v.hi[nt * 16 + r16][kk * 32 + quad * 8];
        short8 vl = *(const short8*)&u.v.lo[nt * 16 + r16][kk * 32 + quad * 8];
#pragma unroll
        for (int mt = 0; mt < 2; mt++) {
          xacc[mt][nt] = __builtin_amdgcn_mfma_f32_16x16x32_bf16(pa[mt], vh, xacc[mt][nt], 0, 0, 0);
          xacc[mt][nt] = __builtin_amdgcn_mfma_f32_16x16x32_bf16(pa[mt], vl, xacc[mt][nt], 0, 0, 0);
        }
      }
    }
    __builtin_amdgcn_s_setprio(0);
    if (half == 0) {
      // Overwrite Ps with cols 64-127 (wave-local rows; own reads above are done
      // in program order, other waves never touch these rows).
#pragma unroll
      for (int mt = 0; mt < 2; mt++)
#pragma unroll
        for (int r = 0; r < 4; r++) {
          int row = rowbase + mt * 16 + quad * 4 + r;
#pragma unroll
          for (int n2 = 0; n2 < 2; n2++) {
            u32 pk = pqh[mt][r][n2];
            Ps[row][(n2 * 2) * 16 + r16] = (u16)(pk & 0xFFFFu);
            Ps[row][(n2 * 2 + 1) * 16 + r16] = (u16)(pk >> 16);
          }
        }
    }
  }

  float mx = -INFINITY;
#pragma unroll
  for (int mt = 0; mt < 2; mt++)
#pragma unroll
    for (int nt = 0; nt < 4; nt++)
#pragma unroll
      for (int r = 0; r < 4; r++) {
        int row = rowbase + mt * 16 + quad * 4 + r;
        xout[((size_t)b * NS + row) * NDM + h * NDK + nt * 16 + r16] = xacc[mt][nt][r];
        mx = fmaxf(mx, xacc[mt][nt][r]);
      }
#pragma unroll
  for (int off = 1; off < 64; off <<= 1) mx = fmaxf(mx, __shfl_xor(mx, off));
  if (lane == 0) xmw[wave] = mx;
  __syncthreads();
  if (tid == 0) {
    float m = fmaxf(fmaxf(xmw[0], xmw[1]), fmaxf(xmw[2], xmw[3]));
    atomicMax(xmax_slot, fenc(m));  // 1 atomic/block (was 4)
  }
}

// ---------------- workspace layout ----------------
constexpr size_t OFF_SCL = 0;                                   // 8 KB (2048 u32)
constexpr size_t OFF_CS  = 8192;                                // colsum 4x1024 int = 16 KB
constexpr size_t OFF_MB  = OFF_CS + 4 * NDM * 4;                // mask bits 128 KB
constexpr size_t OFF_W   = OFF_MB + (size_t)NM * 16;            // i8 weights 4 MB
constexpr size_t OFF_XQ  = OFF_W + 4 * (size_t)NDM * NDM;       // i8 acts 3x8 MB
constexpr size_t OFF_PQ  = OFF_XQ + 3 * (size_t)NM * NDM;       // f32 proj 3x33.5 MB
constexpr size_t OFF_I8  = OFF_PQ + 3 * (size_t)NM * NDM * 4;   // attn i8 qkv 3x8 MB
constexpr size_t OFF_CM  = OFF_I8 + 3 * (size_t)NM * NDM;       // colmax scratch 512 KB
// xout aliases projv (dead after qkv_i8); P is never materialized (flash recompute)

extern "C" void kernel_launch(void* const* d_in, const int* in_sizes, int n_in,
                              void* d_out, int out_size, void* d_ws, size_t ws_size,
                              hipStream_t stream) {
  const float* query = (const float*)d_in[0];
  const float* key = (const float*)d_in[1];
  const float* value = (const float*)d_in[2];
  const int* mask = (const int*)d_in[3];
  const float* Wq = (const float*)d_in[4]; const float* bq = (const float*)d_in[5];
  const float* Wk = (const float*)d_in[6]; const float* bk = (const float*)d_in[7];
  const float* Wv = (const float*)d_in[8]; const float* bv = (const float*)d_in[9];
  const float* Wo = (const float*)d_in[10]; const float* bo = (const float*)d_in[11];

  char* ws = (char*)d_ws;
  float* scl = (float*)(ws + OFF_SCL);
  u32* sclu = (u32*)scl;
  int* colsum = (int*)(ws + OFF_CS);
  u64* mb = (u64*)(ws + OFF_MB);
  i8* wb = (i8*)(ws + OFF_W);        // wq|wk|wv|wo
  i8* wob = wb + 3 * (size_t)NDM * NDM;
  i8* xq = (i8*)(ws + OFF_XQ);       // q|k|v shifted i8 (slot 0 reused for x)
  float* proj = (float*)(ws + OFF_PQ);
  i8* qkv8 = (i8*)(ws + OFF_I8);
  float* cm_part = (float*)(ws + OFF_CM);
  float* xout = proj + 2 * (size_t)NM * NDM;
  i8* vi8 = qkv8 + 2 * (size_t)NM * NDM;

  maskbits_kernel<<<NM / 4, 256, 0, stream>>>(mask, mb, sclu);
  fused_max_kernel<<<dim3(512, 7), 256, 0, stream>>>(query, key, value, Wq, Wk, Wv, Wo, sclu);
  quant_w_i8_kernel<<<dim3(NDM, 4), 256, 0, stream>>>(Wq, Wk, Wv, Wo, wb, colsum, sclu);
  quant_a_kernel<<<dim3(512, 3), 256, 0, stream>>>(query, key, value, xq, sclu, 0);

  gemm_kernel<true><<<dim3(NM / BM, NDM / BN, 3), 256, 0, stream>>>(
      xq, wb, colsum, bq, bk, bv, proj, sclu);

  qkv_i8_kernel<<<dim3(512, 3), 256, 0, stream>>>(proj, qkv8, scl);

  attn_colmax_kernel<<<NB * NH, 256, 0, stream>>>(qkv8, qkv8 + (size_t)NM * NDM, mb, scl,
                                                  cm_part);
  colmax_reduce_kernel<<<NS, 256, 0, stream>>>(cm_part, sclu);
  attn_pv2_kernel<<<NB * NH, 256, 0, stream>>>(qkv8, qkv8 + (size_t)NM * NDM, vi8, mb, scl,
                                               xout, sclu + 7);

  quant_a_kernel<<<dim3(512, 1), 256, 0, stream>>>(xout, xout, xout, xq, sclu, 7);
  gemm_kernel<false><<<dim3(NM / BM, NDM / BN, 1), 256, 0, stream>>>(
      xq, wob, colsum, bo, bo, bo, (float*)d_out, sclu);
}